// Round 1
// baseline (156.252 us; speedup 1.0000x reference)
//
#include <hip/hip_runtime.h>

// QuantizationLayer: num = rint(x * 2^B - 0.5) (round-half-even, matching
// jnp.round); num %= 256; emit B bits MSB-first as floats.
// B=4 path: each input float expands to exactly one float4 -> one coalesced
// 16B store per lane. Memory-bound: 4B read + 4*B B written per element.

__global__ void quant_bits_b4(const float* __restrict__ x,
                              float* __restrict__ out, int n) {
    int i = blockIdx.x * blockDim.x + threadIdx.x;
    if (i >= n) return;
    float v = x[i];
    // rintf -> v_rndne_f32 (round half to even), matches jnp.round exactly
    int num = (int)rintf(v * 16.0f - 0.5f);
    num &= 255;  // emulate uint8 wraparound (num % 256)
    float4 o;
    o.x = (float)((num >> 3) & 1);
    o.y = (float)((num >> 2) & 1);
    o.z = (float)((num >> 1) & 1);
    o.w = (float)( num       & 1);
    reinterpret_cast<float4*>(out)[i] = o;
}

__global__ void quant_bits_generic(const float* __restrict__ x,
                                   float* __restrict__ out, int n,
                                   int B, float step) {
    int i = blockIdx.x * blockDim.x + threadIdx.x;
    if (i >= n) return;
    float v = x[i];
    int num = (int)rintf(v * step - 0.5f);
    num &= 255;
    float* o = out + (size_t)i * (size_t)B;
    for (int j = 0; j < B; ++j) {
        o[j] = (float)((num >> (B - 1 - j)) & 1);
    }
}

extern "C" void kernel_launch(void* const* d_in, const int* in_sizes, int n_in,
                              void* d_out, int out_size, void* d_ws, size_t ws_size,
                              hipStream_t stream) {
    const float* x = (const float*)d_in[0];
    float* out = (float*)d_out;
    int n = in_sizes[0];                 // 4096*2048 = 8388608 input elements
    int B = out_size / n;                // recover B on host: out_size = n*B

    const int block = 256;
    int grid = (n + block - 1) / block;

    if (B == 4) {
        quant_bits_b4<<<grid, block, 0, stream>>>(x, out, n);
    } else {
        float step = (float)(1u << B);
        quant_bits_generic<<<grid, block, 0, stream>>>(x, out, n, B, step);
    }
}